// Round 3
// baseline (3238.913 us; speedup 1.0000x reference)
//
#include <hip/hip_runtime.h>
#include <stdint.h>

// ---------------------------------------------------------------------------
// Seq2seq (2-layer LSTM encoder + attention decoder) on MI355X.
// Numerics: "ph2" = packed split-fp16: u32 = hi(fp16) | lo(fp16)<<16,
//           value = hi + lo * 2^-11.  GEMMs use 3 MFMA products.
// Round 3: per-WG flag sync (no same-address atomic RMW serialization),
//          wave-parallel poll w/o release barrier, y-store off the release
//          path, pre-split ph2 encoder weights for cheap GEMM B-staging.
// ---------------------------------------------------------------------------

typedef _Float16 f16;
typedef f16 f16x8 __attribute__((ext_vector_type(8)));
typedef float f32x4 __attribute__((ext_vector_type(4)));

#define LOSCALE 2048.0f
#define LOINV   (1.0f/2048.0f)

#define B_  128
#define S_  256
#define H_  512

__device__ __forceinline__ uint16_t hbits(f16 h){ union{ f16 f; uint16_t u; } c; c.f=h; return c.u; }

__device__ __forceinline__ uint32_t split_ph2(float x){
  f16 h = (f16)x;
  float r = (x - (float)h) * LOSCALE;
  return (uint32_t)hbits(h) | ((uint32_t)hbits((f16)r) << 16);
}
__device__ __forceinline__ float ph2val(uint32_t p){
  union{ uint16_t u; f16 f; } a, b; a.u = (uint16_t)p; b.u = (uint16_t)(p>>16);
  return (float)a.f + (float)b.f * LOINV;
}

__device__ __forceinline__ void pack_hi_lo(const uint4& a, const uint4& b, uint4& hi, uint4& lo){
  hi = make_uint4((a.x & 0xffffu) | (a.y << 16),
                  (a.z & 0xffffu) | (a.w << 16),
                  (b.x & 0xffffu) | (b.y << 16),
                  (b.z & 0xffffu) | (b.w << 16));
  lo = make_uint4((a.x >> 16) | (a.y & 0xffff0000u),
                  (a.z >> 16) | (a.w & 0xffff0000u),
                  (b.x >> 16) | (b.y & 0xffff0000u),
                  (b.z >> 16) | (b.w & 0xffff0000u));
}

__device__ __forceinline__ void split_pack8(const float* x, uint4& hi, uint4& lo){
  uint16_t h[8], l[8];
#pragma unroll
  for (int e = 0; e < 8; ++e) {
    f16 hh = (f16)x[e];
    float r = (x[e] - (float)hh) * LOSCALE;
    h[e] = hbits(hh); l[e] = hbits((f16)r);
  }
  hi = make_uint4((uint32_t)h[0]|((uint32_t)h[1]<<16), (uint32_t)h[2]|((uint32_t)h[3]<<16),
                  (uint32_t)h[4]|((uint32_t)h[5]<<16), (uint32_t)h[6]|((uint32_t)h[7]<<16));
  lo = make_uint4((uint32_t)l[0]|((uint32_t)l[1]<<16), (uint32_t)l[2]|((uint32_t)l[3]<<16),
                  (uint32_t)l[4]|((uint32_t)l[5]<<16), (uint32_t)l[6]|((uint32_t)l[7]<<16));
}

__device__ __forceinline__ f32x4 mfma16(uint4 a, uint4 b, f32x4 c){
  return __builtin_amdgcn_mfma_f32_16x16x32_f16(
      __builtin_bit_cast(f16x8, a), __builtin_bit_cast(f16x8, b), c, 0, 0, 0);
}

__device__ __forceinline__ float sigm(float x){ return 1.0f/(1.0f + expf(-x)); }

// ---------------------------------------------------------------------------
// K1: embedding gathers (produce ph2 A-matrices)
// ---------------------------------------------------------------------------
__global__ __launch_bounds__(256) void k_embed_src(const int* __restrict__ tok,
    const float* __restrict__ emb, uint32_t* __restrict__ out)
{
  const size_t total = (size_t)S_ * B_ * H_;
  for (size_t i = (size_t)blockIdx.x*256 + threadIdx.x; i < total; i += (size_t)gridDim.x*256) {
    int e = (int)(i & (H_-1)); int row = (int)(i >> 9);
    int b = row & (B_-1), s = row >> 7;
    int t = tok[b*S_ + s];
    out[i] = split_ph2(emb[(size_t)t*H_ + e]);
  }
}

__global__ __launch_bounds__(256) void k_embed_trg(const int* __restrict__ tok,
    const float* __restrict__ emb, uint32_t* __restrict__ out)
{
  int i = blockIdx.x*256 + threadIdx.x;   // 65536
  int e = i & (H_-1), b = i >> 9;
  int t = tok[b];
  out[i] = split_ph2(emb[(size_t)t*H_ + e]);
}

// ---------------------------------------------------------------------------
// K2: GEMM  C[M,N] = A(ph2)[M,K] @ W[N,ldw]^T (+bias0+bias1) (+=C)
// bsplit=1: W is pre-split ph2 (u32). bsplit=0: W is f32, split on stage.
// ---------------------------------------------------------------------------
__global__ __launch_bounds__(256,2) void k_gemm(
    const uint32_t* __restrict__ A, int lda,
    const void* __restrict__ W, int ldw, int bsplit,
    const float* __restrict__ b0, const float* __restrict__ b1,
    float* __restrict__ C, int N, int K, int addC)
{
  __shared__ uint8_t sm[65536];
  const int tid = threadIdx.x;
  const int lane = tid & 63, wv = tid >> 6;
  const int wm = wv >> 1, wn = wv & 1;
  const int bn0 = blockIdx.x * 128, bm0 = blockIdx.y * 128;

  const int srow = tid >> 1;
  const int skh  = (tid & 1) * 32;
  const int smt  = srow >> 4, sr = srow & 15, skt = tid & 1;

  f32x4 acc0[4][4], acc1[4][4];
#pragma unroll
  for (int i = 0; i < 4; ++i)
#pragma unroll
    for (int j = 0; j < 4; ++j) { acc0[i][j] = (f32x4){0,0,0,0}; acc1[i][j] = (f32x4){0,0,0,0}; }

  for (int k0 = 0; k0 < K; k0 += 64) {
    __syncthreads();
    { // stage A (already ph2)
      const uint32_t* ap = A + (size_t)(bm0 + srow) * lda + (k0 + skh);
      uint4 q[8];
#pragma unroll
      for (int e = 0; e < 8; ++e) q[e] = *(const uint4*)(ap + e*4);
#pragma unroll
      for (int kg = 0; kg < 4; ++kg) {
        uint4 hi, lo; pack_hi_lo(q[2*kg], q[2*kg+1], hi, lo);
        uint8_t* dst = sm + (size_t)(smt*2 + skt)*2048 + (size_t)(sr + 16*kg)*16;
        *(uint4*)dst = hi; *(uint4*)(dst + 1024) = lo;
      }
    }
    if (bsplit) { // stage B (pre-split ph2)
      const uint32_t* wp = (const uint32_t*)W + (size_t)(bn0 + srow) * ldw + (k0 + skh);
      uint4 q[8];
#pragma unroll
      for (int e = 0; e < 8; ++e) q[e] = *(const uint4*)(wp + e*4);
#pragma unroll
      for (int kg = 0; kg < 4; ++kg) {
        uint4 hi, lo; pack_hi_lo(q[2*kg], q[2*kg+1], hi, lo);
        uint8_t* dst = sm + 32768 + (size_t)(smt*2 + skt)*2048 + (size_t)(sr + 16*kg)*16;
        *(uint4*)dst = hi; *(uint4*)(dst + 1024) = lo;
      }
    } else { // stage B (split f32 weights)
      const float* wp = (const float*)W + (size_t)(bn0 + srow) * ldw + (k0 + skh);
      float xs[32];
#pragma unroll
      for (int e = 0; e < 8; ++e) { float4 v = *(const float4*)(wp + e*4);
        xs[e*4+0]=v.x; xs[e*4+1]=v.y; xs[e*4+2]=v.z; xs[e*4+3]=v.w; }
#pragma unroll
      for (int kg = 0; kg < 4; ++kg) {
        uint4 hi, lo; split_pack8(xs + kg*8, hi, lo);
        uint8_t* dst = sm + 32768 + (size_t)(smt*2 + skt)*2048 + (size_t)(sr + 16*kg)*16;
        *(uint4*)dst = hi; *(uint4*)(dst + 1024) = lo;
      }
    }
    __syncthreads();

#pragma unroll
    for (int kt = 0; kt < 2; ++kt) {
      uint4 ah[4], al[4];
#pragma unroll
      for (int i = 0; i < 4; ++i) {
        const uint8_t* p = sm + (size_t)(((wm*4+i)*2 + kt))*2048 + lane*16;
        ah[i] = *(const uint4*)p; al[i] = *(const uint4*)(p + 1024);
      }
#pragma unroll
      for (int j = 0; j < 4; ++j) {
        const uint8_t* p = sm + 32768 + (size_t)(((wn*4+j)*2 + kt))*2048 + lane*16;
        uint4 bh = *(const uint4*)p;
        uint4 bl = *(const uint4*)(p + 1024);
#pragma unroll
        for (int i = 0; i < 4; ++i) {
          acc0[i][j] = mfma16(ah[i], bh, acc0[i][j]);
          acc1[i][j] = mfma16(al[i], bh, acc1[i][j]);
          acc1[i][j] = mfma16(ah[i], bl, acc1[i][j]);
        }
      }
    }
  }

#pragma unroll
  for (int i = 0; i < 4; ++i) {
    int row0 = bm0 + (wm*4+i)*16 + ((lane>>4)<<2);
#pragma unroll
    for (int j = 0; j < 4; ++j) {
      int col = bn0 + (wn*4+j)*16 + (lane & 15);
      float bias = 0.f;
      if (b0) bias += b0[col];
      if (b1) bias += b1[col];
      f32x4 v = acc0[i][j] + acc1[i][j] * LOINV;
#pragma unroll
      for (int r = 0; r < 4; ++r) {
        size_t idx = (size_t)(row0 + r) * N + col;
        float out = v[r] + bias;
        if (addC) out += C[idx];
        C[idx] = out;
      }
    }
  }
}

// ---------------------------------------------------------------------------
// K3: persistent LSTM recurrence. Cache-bypass mailbox through LLC.
// Sync: per-WG flag word flags[bg][hs]=s+1 (written after h drain); consumers
// wave-parallel poll the ring's 32 flags (one 128B LLC read / iter).
// hbuf: [2 slots][8 bg][8192 u32 swizzled tile image]
// ---------------------------------------------------------------------------
__global__ __launch_bounds__(256,1) void k_lstm(
    const float* __restrict__ Whh,        // [2048][512]
    const float* __restrict__ xg,         // chunk [nsteps][128][2048] f32
    const int*  __restrict__ lens,
    uint32_t* __restrict__ hbuf,          // [2][8][8192]
    float* __restrict__ cbuf,             // [128][512]
    uint32_t* __restrict__ ybuf,          // [256][128][512] ph2
    uint32_t* __restrict__ flags,         // [8][32]
    int s0, int nsteps)
{
  __shared__ uint8_t sm[163840];          // 128KB Whh frags | 32KB h tile (gates alias)
  uint8_t* htile = sm + 131072;
  float* gates_lds = (float*)(sm + 131072);
  const int tid = threadIdx.x, lane = tid & 63, wv = tid >> 6;
  const int bg = blockIdx.x & 7, hs = blockIdx.x >> 3;

  { // stage Whh slice -> frag-linear hi/lo blocks [nt=g 0..3][kt 0..15]
    const int gcl = tid >> 2;
    const int g = gcl >> 4, c = gcl & 15;
    const int kq = (tid & 3) * 128;
    const float* wrow = Whh + (size_t)(g*512 + hs*16 + c) * 512 + kq;
#pragma unroll 4
    for (int kk = 0; kk < 128; kk += 8) {
      float xs[8];
      float4 v0 = *(const float4*)(wrow + kk);
      float4 v1 = *(const float4*)(wrow + kk + 4);
      xs[0]=v0.x; xs[1]=v0.y; xs[2]=v0.z; xs[3]=v0.w;
      xs[4]=v1.x; xs[5]=v1.y; xs[6]=v1.z; xs[7]=v1.w;
      uint4 hi, lo; split_pack8(xs, hi, lo);
      int k = kq + kk; int kt = k >> 5; int kg = (k >> 3) & 3;
      uint8_t* dst = sm + (size_t)(g*16 + kt)*2048 + (size_t)(c + 16*kg)*16;
      *(uint4*)dst = hi; *(uint4*)(dst + 1024) = lo;
    }
  }

  const int b_l = tid >> 4, uu = tid & 15;
  const int bglob = bg*16 + b_l;
  const int colg = hs*4 + (uu >> 2);
  const size_t myswz = (size_t)b_l*512 + (size_t)((colg ^ b_l)*4 + (uu & 3));
  const size_t bgoff = (size_t)bg*8192;
  float c_reg = cbuf[(size_t)bglob*512 + hs*16 + uu];
  float h_reg = ph2val(hbuf[(size_t)(s0 & 1)*65536 + bgoff + myswz]);
  const int len_b = lens[bglob];
  const int row = lane & 15, qh = lane >> 4;
  const uint32_t* myflag = flags + bg*32 + (lane & 31);
  __syncthreads();

  for (int sl = 0; sl < nsteps; ++sl) {
    const int s = s0 + sl;

    // prefetch this step's x-contribution (overlaps the poll)
    const float* xgp = xg + ((size_t)sl*128 + bglob)*2048 + hs*16 + uu;
    float xv0 = xgp[0], xv1 = xgp[512], xv2 = xgp[1024], xv3 = xgp[1536];

    if (sl > 0) {
      // wave-parallel poll: lanes 0..31 each watch one producer flag
      while (1) {
        uint32_t f = __hip_atomic_load(myflag, __ATOMIC_RELAXED, __HIP_MEMORY_SCOPE_SYSTEM);
        if (__all((int)(f >= (uint32_t)s))) break;
        __builtin_amdgcn_s_sleep(1);
      }
    }

    { // stage h tile (32KB) from LLC, cache-bypass, coalesced, linear copy
      const uint64_t* src = (const uint64_t*)(hbuf + (size_t)(s & 1)*65536 + bgoff);
      uint64_t* dst = (uint64_t*)htile;
      uint64_t v[16];
#pragma unroll
      for (int e = 0; e < 16; ++e)
        v[e] = __hip_atomic_load(src + tid + e*256, __ATOMIC_RELAXED, __HIP_MEMORY_SCOPE_SYSTEM);
#pragma unroll
      for (int e = 0; e < 16; ++e)
        dst[tid + e*256] = v[e];
    }
    __syncthreads();                       // A: tile staged

    f32x4 a0 = (f32x4){0,0,0,0}, a1 = (f32x4){0,0,0,0}, a2 = (f32x4){0,0,0,0};
    const uint8_t* hrowp = htile + (size_t)row*2048;
#pragma unroll
    for (int kt = 0; kt < 16; ++kt) {
      int g0 = kt*8 + qh*2;
      uint4 pa = *(const uint4*)(hrowp + (((g0)     ^ row) << 4));
      uint4 pb = *(const uint4*)(hrowp + (((g0 + 1) ^ row) << 4));
      uint4 ah, al; pack_hi_lo(pa, pb, ah, al);
      const uint8_t* bp = sm + (size_t)(wv*16 + kt)*2048 + lane*16;
      uint4 bh = *(const uint4*)bp, bl = *(const uint4*)(bp + 1024);
      a0 = mfma16(ah, bh, a0);
      a1 = mfma16(al, bh, a1);
      a2 = mfma16(ah, bl, a2);
    }
    __syncthreads();                       // B: tile reads done
    {
      int col = lane & 15, rbase = (lane >> 4) << 2;
#pragma unroll
      for (int r = 0; r < 4; ++r)
        gates_lds[(size_t)(wv*16 + rbase + r)*16 + col] = a0[r] + (a1[r] + a2[r])*LOINV;
    }
    __syncthreads();                       // C: gates exchanged

    float gi = gates_lds[(size_t)(0*16 + b_l)*16 + uu] + xv0;
    float gf = gates_lds[(size_t)(1*16 + b_l)*16 + uu] + xv1;
    float gg = gates_lds[(size_t)(2*16 + b_l)*16 + uu] + xv2;
    float go = gates_lds[(size_t)(3*16 + b_l)*16 + uu] + xv3;
    float cn = sigm(gf)*c_reg + sigm(gi)*tanhf(gg);
    float hn = sigm(go)*tanhf(cn);
    bool m = (s < len_b);
    c_reg = m ? cn : c_reg;
    h_reg = m ? hn : h_reg;
    float yv = m ? hn : 0.f;

    // release: h mailbox write -> drain -> WG barrier -> flag
    __hip_atomic_store(hbuf + (size_t)((s + 1) & 1)*65536 + bgoff + myswz,
                       split_ph2(h_reg), __ATOMIC_RELAXED, __HIP_MEMORY_SCOPE_SYSTEM);
    asm volatile("s_waitcnt vmcnt(0)" ::: "memory");
    __syncthreads();                       // D: all h writes in LLC
    if (tid == 0)
      __hip_atomic_store(flags + bg*32 + hs, (uint32_t)(s + 1),
                         __ATOMIC_RELAXED, __HIP_MEMORY_SCOPE_SYSTEM);
    // y store off the release path
    ybuf[(size_t)s*65536 + (size_t)bglob*512 + hs*16 + uu] = split_ph2(yv);
  }
  cbuf[(size_t)bglob*512 + hs*16 + uu] = c_reg;
}

// ---------------------------------------------------------------------------
// small epilogue kernels
// ---------------------------------------------------------------------------
__global__ __launch_bounds__(256) void k_pack2(const float* __restrict__ a,
    const float* __restrict__ b, uint32_t* __restrict__ out)
{
  int i = blockIdx.x*256 + threadIdx.x;
  int bb = i >> 10, k = i & 1023;
  float x = (k < 512) ? a[(size_t)bb*512 + k] : b[(size_t)bb*512 + k - 512];
  out[i] = split_ph2(x);
}

__global__ __launch_bounds__(256) void k_pack1(const float* __restrict__ a,
    uint32_t* __restrict__ out)
{ int i = blockIdx.x*256 + threadIdx.x; out[i] = split_ph2(a[i]); }

__global__ __launch_bounds__(256) void k_tanh_split(const float* __restrict__ c,
    uint32_t* __restrict__ hp)
{ int i = blockIdx.x*256 + threadIdx.x; hp[i] = split_ph2(tanhf(c[i])); }

__global__ __launch_bounds__(256) void k_dec_cell(const float* __restrict__ g,
    const float* __restrict__ cdec, float* __restrict__ hout, float* __restrict__ dh)
{
  int i = blockIdx.x*256 + threadIdx.x;     // 65536
  int b = i >> 9, u = i & 511;
  const float* gb = g + (size_t)b*2048;
  float c = sigm(gb[512 + u])*cdec[i] + sigm(gb[u])*tanhf(gb[1024 + u]);
  float h = sigm(gb[1536 + u])*tanhf(c);
  hout[i] = h; dh[i] = h;
}

// scores -> masked softmax -> context (one block per batch row)
__global__ __launch_bounds__(256) void k_attn(const uint32_t* __restrict__ y1,
    const float* __restrict__ h, const int* __restrict__ lens,
    float* __restrict__ ctx, float* __restrict__ dctx)
{
  __shared__ float hsh[512];
  __shared__ float sc[256];
  __shared__ float red[8];
  const int b = blockIdx.x, tid = threadIdx.x, lane = tid & 63, wv = tid >> 6;
  hsh[tid]       = h[(size_t)b*512 + tid];
  hsh[tid + 256] = h[(size_t)b*512 + tid + 256];
  const int len = lens[b];
  __syncthreads();

  for (int it = 0; it < 64; ++it) {
    int s = wv*64 + it;
    const uint32_t* yp = y1 + ((size_t)s*128 + b)*512 + lane*8;
    uint4 p0 = *(const uint4*)yp, p1 = *(const uint4*)(yp + 4);
    uint32_t pv[8] = {p0.x,p0.y,p0.z,p0.w,p1.x,p1.y,p1.z,p1.w};
    float d = 0.f;
#pragma unroll
    for (int e = 0; e < 8; ++e) d += ph2val(pv[e]) * hsh[lane*8 + e];
    for (int off = 32; off; off >>= 1) d += __shfl_xor(d, off);
    if (lane == 0) sc[s] = d;
  }
  __syncthreads();

  float v = (tid < len) ? sc[tid] : -INFINITY;
  float mx = v;
  for (int off = 32; off; off >>= 1) mx = fmaxf(mx, __shfl_xor(mx, off));
  if (lane == 0) red[wv] = mx;
  __syncthreads();
  mx = fmaxf(fmaxf(red[0], red[1]), fmaxf(red[2], red[3]));
  float e = (tid < len) ? expf(v - mx) : 0.f;
  float ssum = e;
  for (int off = 32; off; off >>= 1) ssum += __shfl_xor(ssum, off);
  if (lane == 0) red[4 + wv] = ssum;
  __syncthreads();
  float tot = red[4] + red[5] + red[6] + red[7];
  __syncthreads();
  sc[tid] = e / tot;
  __syncthreads();

  float acc0 = 0.f, acc1 = 0.f;
  for (int s = 0; s < 256; ++s) {
    float w = sc[s];
    const uint32_t* yp = y1 + ((size_t)s*128 + b)*512;
    acc0 += w * ph2val(yp[tid]);
    acc1 += w * ph2val(yp[tid + 256]);
  }
  ctx [(size_t)b*512 + tid]       = acc0;  ctx [(size_t)b*512 + tid + 256] = acc1;
  dctx[(size_t)b*512 + tid]       = acc0;  dctx[(size_t)b*512 + tid + 256] = acc1;
}

__global__ __launch_bounds__(256) void k_argmax(const float* __restrict__ logits,
    float* __restrict__ out)
{
  __shared__ float bv[256];
  __shared__ int   bi[256];
  const int b = blockIdx.x, tid = threadIdx.x;
  const float* L = logits + (size_t)b*32000;
  float best = -INFINITY; int idx = 0;
  for (int i = tid; i < 32000; i += 256) {
    float v = L[i];
    if (v > best) { best = v; idx = i; }
  }
  bv[tid] = best; bi[tid] = idx;
  __syncthreads();
  for (int sft = 128; sft; sft >>= 1) {
    if (tid < sft) {
      if (bv[tid+sft] > bv[tid] || (bv[tid+sft] == bv[tid] && bi[tid+sft] < bi[tid])) {
        bv[tid] = bv[tid+sft]; bi[tid] = bi[tid+sft];
      }
    }
    __syncthreads();
  }
  if (tid == 0) out[b] = (float)bi[0];
}

// ---------------------------------------------------------------------------
// launcher
// ---------------------------------------------------------------------------
extern "C" void kernel_launch(void* const* d_in, const int* in_sizes, int n_in,
                              void* d_out, int out_size, void* d_ws, size_t ws_size,
                              hipStream_t stream)
{
  (void)in_sizes; (void)n_in; (void)out_size;
  const int*   src_tokens = (const int*)  d_in[0];
  const int*   src_lens   = (const int*)  d_in[1];
  const int*   trg_tokens = (const int*)  d_in[2];
  const float* src_emb    = (const float*)d_in[3];
  const float* trg_emb    = (const float*)d_in[4];
  const float* Wih0 = (const float*)d_in[5];
  const float* Whh0 = (const float*)d_in[6];
  const float* bih0 = (const float*)d_in[7];
  const float* bhh0 = (const float*)d_in[8];
  const float* Wih1 = (const float*)d_in[9];
  const float* Whh1 = (const float*)d_in[10];
  const float* bih1 = (const float*)d_in[11];
  const float* bhh1 = (const float*)d_in[12];
  const float* dWih = (const float*)d_in[13];
  const float* dWhh = (const float*)d_in[14];
  const float* dbih = (const float*)d_in[15];
  const float* dbhh = (const float*)d_in[16];
  const float* Winit= (const float*)d_in[17];
  const float* binit= (const float*)d_in[18];
  const float* Whid = (const float*)d_in[19];
  const float* bhid = (const float*)d_in[20];
  const float* Wout = (const float*)d_in[21];
  const float* bout = (const float*)d_in[22];

  uint8_t* ws = (uint8_t*)d_ws;
  constexpr size_t MBs = 1ull << 20;
  constexpr size_t OFF_AP    = 0;                         // 64MB ph2 (src embeds; later Y1)
  constexpr size_t OFF_Y0    = 64*MBs;                    // 64MB ph2
  constexpr size_t OFF_XG    = 128*MBs;                   // 64MB f32 (Xg chunk)
  constexpr size_t OFF_HBUF  = 192*MBs;                   // 512KB
  constexpr size_t OFF_CB0   = OFF_HBUF  + 512*1024;      // 256KB
  constexpr size_t OFF_CB1   = OFF_CB0   + 256*1024;      // 256KB
  constexpr size_t OFF_FLG   = OFF_CB1   + 256*1024;      // 4KB
  constexpr size_t OFF_PK    = OFF_FLG   + 4096;          // 512KB
  constexpr size_t OFF_CDEC  = OFF_PK    + 512*1024;      // 256KB
  constexpr size_t OFF_HDECP = OFF_CDEC  + 256*1024;      // 256KB ph2
  constexpr size_t OFF_EMBP  = OFF_HDECP + 256*1024;      // 256KB ph2
  constexpr size_t OFF_G     = OFF_EMBP  + 256*1024;      // 1MB f32
  constexpr size_t OFF_HDEC2 = OFF_G     + 1*MBs;         // 256KB f32
  constexpr size_t OFF_CTX   = OFF_HDEC2 + 256*1024;      // 256KB f32
  constexpr size_t OFF_AVEC  = OFF_CTX   + 256*1024;      // 256KB f32
  constexpr size_t OFF_AVECP = OFF_AVEC  + 256*1024;      // 256KB ph2
  constexpr size_t OFF_LOG   = OFF_AVECP + 256*1024;      // 16MB f32
  constexpr size_t OFF_WP0   = OFF_LOG   + 16*MBs;        // 4MB ph2 (Wih0)
  constexpr size_t OFF_WP1   = OFF_WP0   + 4*MBs;         // 4MB ph2 (Wih1)
  constexpr size_t WS_NEED_WP = OFF_WP1 + 4*MBs;

  uint32_t* Ap    = (uint32_t*)(ws + OFF_AP);
  uint32_t* Y0    = (uint32_t*)(ws + OFF_Y0);
  uint32_t* Y1    = (uint32_t*)(ws + OFF_AP);     // reuse after layer 0
  float*    Xg    = (float*)   (ws + OFF_XG);
  uint32_t* hbuf  = (uint32_t*)(ws + OFF_HBUF);
  float*    cb0   = (float*)   (ws + OFF_CB0);
  float*    cb1   = (float*)   (ws + OFF_CB1);
  uint32_t* flg   = (uint32_t*)(ws + OFF_FLG);
  uint32_t* pk    = (uint32_t*)(ws + OFF_PK);
  float*    cdec  = (float*)   (ws + OFF_CDEC);
  uint32_t* hdecp = (uint32_t*)(ws + OFF_HDECP);
  uint32_t* embp  = (uint32_t*)(ws + OFF_EMBP);
  float*    g     = (float*)   (ws + OFF_G);
  float*    hdec2 = (float*)   (ws + OFF_HDEC2);
  float*    ctx   = (float*)   (ws + OFF_CTX);
  float*    avec  = (float*)   (ws + OFF_AVEC);
  uint32_t* avecp = (uint32_t*)(ws + OFF_AVECP);
  float*    logit = (float*)   (ws + OFF_LOG);
  uint32_t* Wp0   = (uint32_t*)(ws + OFF_WP0);
  uint32_t* Wp1   = (uint32_t*)(ws + OFF_WP1);
  float*    dout  = (float*)   d_out;

  const bool useWp = (ws_size >= WS_NEED_WP);

  // ---- one-time: pre-split encoder input weights to ph2 ----
  if (useWp) {
    k_pack1<<<4096, 256, 0, stream>>>(Wih0, Wp0);   // 2048x512
    k_pack1<<<4096, 256, 0, stream>>>(Wih1, Wp1);
  }

  // ---- encoder layer 0 ----
  hipMemsetAsync(flg,  0, 1024, stream);
  hipMemsetAsync(hbuf, 0, 2*65536*4, stream);
  hipMemsetAsync(cb0,  0, 65536*4, stream);
  k_embed_src<<<2048, 256, 0, stream>>>(src_tokens, src_emb, Ap);
  for (int c = 0; c < 4; ++c) {
    int s0 = c * 64;
    if (useWp)
      k_gemm<<<dim3(16, 64), 256, 0, stream>>>(Ap + (size_t)s0*128*512, 512,
          Wp0, 512, 1, bih0, bhh0, Xg, 2048, 512, 0);
    else
      k_gemm<<<dim3(16, 64), 256, 0, stream>>>(Ap + (size_t)s0*128*512, 512,
          Wih0, 512, 0, bih0, bhh0, Xg, 2048, 512, 0);
    k_lstm<<<256, 256, 0, stream>>>(Whh0, Xg, src_lens, hbuf, cb0, Y0, flg, s0, 64);
  }
  // ---- encoder layer 1 ----
  hipMemsetAsync(flg,  0, 1024, stream);
  hipMemsetAsync(hbuf, 0, 2*65536*4, stream);
  hipMemsetAsync(cb1,  0, 65536*4, stream);
  for (int c = 0; c < 4; ++c) {
    int s0 = c * 64;
    if (useWp)
      k_gemm<<<dim3(16, 64), 256, 0, stream>>>(Y0 + (size_t)s0*128*512, 512,
          Wp1, 512, 1, bih1, bhh1, Xg, 2048, 512, 0);
    else
      k_gemm<<<dim3(16, 64), 256, 0, stream>>>(Y0 + (size_t)s0*128*512, 512,
          Wih1, 512, 0, bih1, bhh1, Xg, 2048, 512, 0);
    k_lstm<<<256, 256, 0, stream>>>(Whh1, Xg, src_lens, hbuf, cb1, Y1, flg, s0, 64);
  }

  // ---- decoder init ----
  k_pack2<<<512, 256, 0, stream>>>(cb0, cb1, pk);
  k_gemm<<<dim3(4, 1), 256, 0, stream>>>(pk, 1024, Winit, 1024, 0, binit, nullptr,
      cdec, 512, 1024, 0);
  k_tanh_split<<<256, 256, 0, stream>>>(cdec, hdecp);

  // ---- decoder LSTM step ----
  k_embed_trg<<<256, 256, 0, stream>>>(trg_tokens, trg_emb, embp);
  k_gemm<<<dim3(16, 1), 256, 0, stream>>>(embp, 512, dWih, 1024, 0, dbih, dbhh,
      g, 2048, 512, 0);
  k_gemm<<<dim3(16, 1), 256, 0, stream>>>(hdecp, 512, dWhh, 512, 0, nullptr, nullptr,
      g, 2048, 512, 1);
  k_dec_cell<<<256, 256, 0, stream>>>(g, cdec, hdec2, dout + 65536);

  // ---- attention ----
  k_attn<<<128, 256, 0, stream>>>(Y1, hdec2, src_lens, ctx, dout);

  // ---- output projection + argmax ----
  k_pack2<<<512, 256, 0, stream>>>(hdec2, ctx, pk);
  k_gemm<<<dim3(4, 1), 256, 0, stream>>>(pk, 1024, Whid, 1024, 0, bhid, nullptr,
      avec, 512, 1024, 0);
  k_pack1<<<256, 256, 0, stream>>>(avec, avecp);
  k_gemm<<<dim3(250, 1), 256, 0, stream>>>(avecp, 512, Wout, 512, 0, bout, nullptr,
      logit, 32000, 512, 0);
  k_argmax<<<128, 256, 0, stream>>>(logit, dout + 131072);
}

// Round 4
// 2688.340 us; speedup vs baseline: 1.2048x; 1.2048x over previous
//
#include <hip/hip_runtime.h>
#include <stdint.h>

// ---------------------------------------------------------------------------
// Seq2seq (2-layer LSTM encoder + attention decoder) on MI355X.
// Numerics: "ph2" = packed split-fp16: u32 = hi(fp16) | lo(fp16)<<16,
//           value = hi + lo * 2^-11.  GEMMs use 3 MFMA products.
// Round 4: k_lstm — mailbox stored as pre-split hi/lo planes (no unpack VALU
//          in k-loop), Whh slice held in REGISTERS (LDS 160->36KB, half the
//          per-step LDS traffic), wave0 poll + barrier release (round-2 style),
//          fast __expf-based sigmoid/tanh.
// ---------------------------------------------------------------------------

typedef _Float16 f16;
typedef f16 f16x8 __attribute__((ext_vector_type(8)));
typedef float f32x4 __attribute__((ext_vector_type(4)));

#define LOSCALE 2048.0f
#define LOINV   (1.0f/2048.0f)

#define B_  128
#define S_  256
#define H_  512

__device__ __forceinline__ uint16_t hbits(f16 h){ union{ f16 f; uint16_t u; } c; c.f=h; return c.u; }

__device__ __forceinline__ uint32_t split_ph2(float x){
  f16 h = (f16)x;
  float r = (x - (float)h) * LOSCALE;
  return (uint32_t)hbits(h) | ((uint32_t)hbits((f16)r) << 16);
}
__device__ __forceinline__ float ph2val(uint32_t p){
  union{ uint16_t u; f16 f; } a, b; a.u = (uint16_t)p; b.u = (uint16_t)(p>>16);
  return (float)a.f + (float)b.f * LOINV;
}

__device__ __forceinline__ void pack_hi_lo(const uint4& a, const uint4& b, uint4& hi, uint4& lo){
  hi = make_uint4((a.x & 0xffffu) | (a.y << 16),
                  (a.z & 0xffffu) | (a.w << 16),
                  (b.x & 0xffffu) | (b.y << 16),
                  (b.z & 0xffffu) | (b.w << 16));
  lo = make_uint4((a.x >> 16) | (a.y & 0xffff0000u),
                  (a.z >> 16) | (a.w & 0xffff0000u),
                  (b.x >> 16) | (b.y & 0xffff0000u),
                  (b.z >> 16) | (b.w & 0xffff0000u));
}

__device__ __forceinline__ void split_pack8(const float* x, uint4& hi, uint4& lo){
  uint16_t h[8], l[8];
#pragma unroll
  for (int e = 0; e < 8; ++e) {
    f16 hh = (f16)x[e];
    float r = (x[e] - (float)hh) * LOSCALE;
    h[e] = hbits(hh); l[e] = hbits((f16)r);
  }
  hi = make_uint4((uint32_t)h[0]|((uint32_t)h[1]<<16), (uint32_t)h[2]|((uint32_t)h[3]<<16),
                  (uint32_t)h[4]|((uint32_t)h[5]<<16), (uint32_t)h[6]|((uint32_t)h[7]<<16));
  lo = make_uint4((uint32_t)l[0]|((uint32_t)l[1]<<16), (uint32_t)l[2]|((uint32_t)l[3]<<16),
                  (uint32_t)l[4]|((uint32_t)l[5]<<16), (uint32_t)l[6]|((uint32_t)l[7]<<16));
}

__device__ __forceinline__ f32x4 mfma16(uint4 a, uint4 b, f32x4 c){
  return __builtin_amdgcn_mfma_f32_16x16x32_f16(
      __builtin_bit_cast(f16x8, a), __builtin_bit_cast(f16x8, b), c, 0, 0, 0);
}

__device__ __forceinline__ float sigm(float x){ return 1.0f/(1.0f + expf(-x)); }
// fast, NaN-safe variants for the hot recurrence
__device__ __forceinline__ float fsigm(float x){ return 1.0f/(1.0f + __expf(-x)); }
__device__ __forceinline__ float ftanh(float x){
  float ax = fabsf(x);
  float e = __expf(-2.0f*ax);
  float r = (1.0f - e)/(1.0f + e);
  return copysignf(r, x);
}

// ---------------------------------------------------------------------------
// K1: embedding gathers (produce ph2 A-matrices)
// ---------------------------------------------------------------------------
__global__ __launch_bounds__(256) void k_embed_src(const int* __restrict__ tok,
    const float* __restrict__ emb, uint32_t* __restrict__ out)
{
  const size_t total = (size_t)S_ * B_ * H_;
  for (size_t i = (size_t)blockIdx.x*256 + threadIdx.x; i < total; i += (size_t)gridDim.x*256) {
    int e = (int)(i & (H_-1)); int row = (int)(i >> 9);
    int b = row & (B_-1), s = row >> 7;
    int t = tok[b*S_ + s];
    out[i] = split_ph2(emb[(size_t)t*H_ + e]);
  }
}

__global__ __launch_bounds__(256) void k_embed_trg(const int* __restrict__ tok,
    const float* __restrict__ emb, uint32_t* __restrict__ out)
{
  int i = blockIdx.x*256 + threadIdx.x;   // 65536
  int e = i & (H_-1), b = i >> 9;
  int t = tok[b];
  out[i] = split_ph2(emb[(size_t)t*H_ + e]);
}

// ---------------------------------------------------------------------------
// K2: GEMM  C[M,N] = A(ph2)[M,K] @ W[N,ldw]^T (+bias0+bias1) (+=C)
// bsplit=1: W is pre-split ph2 (u32). bsplit=0: W is f32, split on stage.
// ---------------------------------------------------------------------------
__global__ __launch_bounds__(256,2) void k_gemm(
    const uint32_t* __restrict__ A, int lda,
    const void* __restrict__ W, int ldw, int bsplit,
    const float* __restrict__ b0, const float* __restrict__ b1,
    float* __restrict__ C, int N, int K, int addC)
{
  __shared__ uint8_t sm[65536];
  const int tid = threadIdx.x;
  const int lane = tid & 63, wv = tid >> 6;
  const int wm = wv >> 1, wn = wv & 1;
  const int bn0 = blockIdx.x * 128, bm0 = blockIdx.y * 128;

  const int srow = tid >> 1;
  const int skh  = (tid & 1) * 32;
  const int smt  = srow >> 4, sr = srow & 15, skt = tid & 1;

  f32x4 acc0[4][4], acc1[4][4];
#pragma unroll
  for (int i = 0; i < 4; ++i)
#pragma unroll
    for (int j = 0; j < 4; ++j) { acc0[i][j] = (f32x4){0,0,0,0}; acc1[i][j] = (f32x4){0,0,0,0}; }

  for (int k0 = 0; k0 < K; k0 += 64) {
    __syncthreads();
    { // stage A (already ph2)
      const uint32_t* ap = A + (size_t)(bm0 + srow) * lda + (k0 + skh);
      uint4 q[8];
#pragma unroll
      for (int e = 0; e < 8; ++e) q[e] = *(const uint4*)(ap + e*4);
#pragma unroll
      for (int kg = 0; kg < 4; ++kg) {
        uint4 hi, lo; pack_hi_lo(q[2*kg], q[2*kg+1], hi, lo);
        uint8_t* dst = sm + (size_t)(smt*2 + skt)*2048 + (size_t)(sr + 16*kg)*16;
        *(uint4*)dst = hi; *(uint4*)(dst + 1024) = lo;
      }
    }
    if (bsplit) { // stage B (pre-split ph2)
      const uint32_t* wp = (const uint32_t*)W + (size_t)(bn0 + srow) * ldw + (k0 + skh);
      uint4 q[8];
#pragma unroll
      for (int e = 0; e < 8; ++e) q[e] = *(const uint4*)(wp + e*4);
#pragma unroll
      for (int kg = 0; kg < 4; ++kg) {
        uint4 hi, lo; pack_hi_lo(q[2*kg], q[2*kg+1], hi, lo);
        uint8_t* dst = sm + 32768 + (size_t)(smt*2 + skt)*2048 + (size_t)(sr + 16*kg)*16;
        *(uint4*)dst = hi; *(uint4*)(dst + 1024) = lo;
      }
    } else { // stage B (split f32 weights)
      const float* wp = (const float*)W + (size_t)(bn0 + srow) * ldw + (k0 + skh);
      float xs[32];
#pragma unroll
      for (int e = 0; e < 8; ++e) { float4 v = *(const float4*)(wp + e*4);
        xs[e*4+0]=v.x; xs[e*4+1]=v.y; xs[e*4+2]=v.z; xs[e*4+3]=v.w; }
#pragma unroll
      for (int kg = 0; kg < 4; ++kg) {
        uint4 hi, lo; split_pack8(xs + kg*8, hi, lo);
        uint8_t* dst = sm + 32768 + (size_t)(smt*2 + skt)*2048 + (size_t)(sr + 16*kg)*16;
        *(uint4*)dst = hi; *(uint4*)(dst + 1024) = lo;
      }
    }
    __syncthreads();

#pragma unroll
    for (int kt = 0; kt < 2; ++kt) {
      uint4 ah[4], al[4];
#pragma unroll
      for (int i = 0; i < 4; ++i) {
        const uint8_t* p = sm + (size_t)(((wm*4+i)*2 + kt))*2048 + lane*16;
        ah[i] = *(const uint4*)p; al[i] = *(const uint4*)(p + 1024);
      }
#pragma unroll
      for (int j = 0; j < 4; ++j) {
        const uint8_t* p = sm + 32768 + (size_t)(((wn*4+j)*2 + kt))*2048 + lane*16;
        uint4 bh = *(const uint4*)p;
        uint4 bl = *(const uint4*)(p + 1024);
#pragma unroll
        for (int i = 0; i < 4; ++i) {
          acc0[i][j] = mfma16(ah[i], bh, acc0[i][j]);
          acc1[i][j] = mfma16(al[i], bh, acc1[i][j]);
          acc1[i][j] = mfma16(ah[i], bl, acc1[i][j]);
        }
      }
    }
  }

#pragma unroll
  for (int i = 0; i < 4; ++i) {
    int row0 = bm0 + (wm*4+i)*16 + ((lane>>4)<<2);
#pragma unroll
    for (int j = 0; j < 4; ++j) {
      int col = bn0 + (wn*4+j)*16 + (lane & 15);
      float bias = 0.f;
      if (b0) bias += b0[col];
      if (b1) bias += b1[col];
      f32x4 v = acc0[i][j] + acc1[i][j] * LOINV;
#pragma unroll
      for (int r = 0; r < 4; ++r) {
        size_t idx = (size_t)(row0 + r) * N + col;
        float out = v[r] + bias;
        if (addC) out += C[idx];
        C[idx] = out;
      }
    }
  }
}

// ---------------------------------------------------------------------------
// K3: persistent LSTM recurrence. LLC cache-bypass mailbox, PRE-SPLIT layout.
// Mailbox per bg (8192 u32 = 32KB): element (row r 0..15, col c 0..511):
//   oct = c>>3, word = (c&7)>>1, plane = (hi:0, lo:1)
//   u32 idx = r*512 + plane*256 + ((oct ^ r) << 2) + word
//   hi-word of pair = hi(c_even) | hi(c_odd)<<16; lo-word likewise.
// Whh slice (this WG's 64 gate cols) lives in REGISTERS (32 uint4 / lane).
// ---------------------------------------------------------------------------
__global__ __launch_bounds__(256,1) void k_lstm(
    const float* __restrict__ Whh,        // [2048][512] f32
    const float* __restrict__ xg,         // chunk [nsteps][128][2048] f32
    const int*  __restrict__ lens,
    uint32_t* __restrict__ hbuf,          // [2][8][8192]
    float* __restrict__ cbuf,             // [128][512]
    uint32_t* __restrict__ ybuf,          // [256][128][512] ph2
    uint32_t* __restrict__ flags,         // [8][32]
    int s0, int nsteps)
{
  __shared__ uint64_t htile64[4096];      // 32KB h tile (split-plane image)
  __shared__ float gates_lds[1024];       // 4KB gate exchange (separate!)
  uint8_t* htile = (uint8_t*)htile64;
  const int tid = threadIdx.x, lane = tid & 63, wv = tid >> 6;
  const int bg = blockIdx.x & 7, hs = blockIdx.x >> 3;
  const int row = lane & 15, qh = lane >> 4;

  // ---- Whh slice -> registers (once per chunk) ----
  // B-frag for kt: lane holds Whh[wv*512 + hs*16 + (lane&15)][kt*32 + qh*8 .. +8]
  uint4 wbh[16], wbl[16];
  {
    const float* wrow = Whh + (size_t)(wv*512 + hs*16 + row) * 512 + qh*8;
#pragma unroll
    for (int kt = 0; kt < 16; ++kt) {
      float xs[8];
      float4 v0 = *(const float4*)(wrow + kt*32);
      float4 v1 = *(const float4*)(wrow + kt*32 + 4);
      xs[0]=v0.x; xs[1]=v0.y; xs[2]=v0.z; xs[3]=v0.w;
      xs[4]=v1.x; xs[5]=v1.y; xs[6]=v1.z; xs[7]=v1.w;
      split_pack8(xs, wbh[kt], wbl[kt]);
    }
  }

  const int b_l = tid >> 4, uu = tid & 15;
  const int bglob = bg*16 + b_l;
  const size_t bgoff = (size_t)bg*8192;
  const int oct_p = hs*2 + (uu >> 3);              // producer oct
  const size_t widx = (size_t)b_l*512 + (size_t)(uu & 1)*256
                    + (size_t)((oct_p ^ b_l) << 2) + (size_t)((uu & 7) >> 1);
  float c_reg = cbuf[(size_t)bglob*512 + hs*16 + uu];
  float h_reg;
  { // init h from split-plane mailbox (kernel-boundary acquire makes it visible)
    size_t ib = (size_t)(s0 & 1)*65536 + bgoff + (size_t)b_l*512
              + (size_t)((oct_p ^ b_l) << 2) + (size_t)((uu & 7) >> 1);
    uint32_t hiw = hbuf[ib];
    uint32_t low = hbuf[ib + 256];
    int sh = (uu & 1) * 16;
    union{ uint16_t u; f16 f; } ch, cl;
    ch.u = (uint16_t)(hiw >> sh); cl.u = (uint16_t)(low >> sh);
    h_reg = (float)ch.f + (float)cl.f * LOINV;
  }
  const int len_b = lens[bglob];
  __syncthreads();

  for (int sl = 0; sl < nsteps; ++sl) {
    const int s = s0 + sl;

    // prefetch this step's x-contribution (overlaps the poll)
    const float* xgp = xg + ((size_t)sl*128 + bglob)*2048 + hs*16 + uu;
    float xv0 = xgp[0], xv1 = xgp[512], xv2 = xgp[1024], xv3 = xgp[1536];

    if (sl > 0) {
      if (wv == 0) {       // wave0 polls all 32 producer flags
        const uint32_t* fp = flags + bg*32 + (lane & 31);
        while (1) {
          uint32_t f = __hip_atomic_load(fp, __ATOMIC_RELAXED, __HIP_MEMORY_SCOPE_SYSTEM);
          if (__all((int)(f >= (uint32_t)s))) break;
          __builtin_amdgcn_s_sleep(1);
        }
      }
      __syncthreads();                   // E: release all waves
    }

    { // stage h tile (32KB) from LLC, cache-bypass, linear copy
      const uint64_t* src = (const uint64_t*)(hbuf + (size_t)(s & 1)*65536 + bgoff);
      uint64_t v[16];
#pragma unroll
      for (int e = 0; e < 16; ++e)
        v[e] = __hip_atomic_load(src + tid + e*256, __ATOMIC_RELAXED, __HIP_MEMORY_SCOPE_SYSTEM);
#pragma unroll
      for (int e = 0; e < 16; ++e)
        htile64[tid + e*256] = v[e];
    }
    __syncthreads();                     // A: tile staged

    // k-loop: 2 ds_read_b128 + 3 MFMA per kt, zero unpack VALU
    f32x4 a0 = (f32x4){0,0,0,0}, a1 = (f32x4){0,0,0,0}, a2 = (f32x4){0,0,0,0};
    const uint8_t* hrowp = htile + (size_t)row*2048;
#pragma unroll
    for (int kt = 0; kt < 16; ++kt) {
      int oct = kt*4 + qh;
      const uint8_t* p = hrowp + (((oct ^ row)) << 4);
      uint4 ah = *(const uint4*)p;             // hi plane
      uint4 al = *(const uint4*)(p + 1024);    // lo plane
      a0 = mfma16(ah, wbh[kt], a0);
      a1 = mfma16(al, wbh[kt], a1);
      a2 = mfma16(ah, wbl[kt], a2);
    }
    { // C frag -> gate exchange (separate LDS region, no tile hazard)
      int col = lane & 15, rbase = (lane >> 4) << 2;
#pragma unroll
      for (int r = 0; r < 4; ++r)
        gates_lds[(size_t)(wv*16 + rbase + r)*16 + col] = a0[r] + (a1[r] + a2[r])*LOINV;
    }
    __syncthreads();                     // C: gates exchanged (also fences tile reads)

    float gi = gates_lds[(size_t)(0*16 + b_l)*16 + uu] + xv0;
    float gf = gates_lds[(size_t)(1*16 + b_l)*16 + uu] + xv1;
    float gg = gates_lds[(size_t)(2*16 + b_l)*16 + uu] + xv2;
    float go = gates_lds[(size_t)(3*16 + b_l)*16 + uu] + xv3;
    float cn = fsigm(gf)*c_reg + fsigm(gi)*ftanh(gg);
    float hn = fsigm(go)*ftanh(cn);
    bool m = (s < len_b);
    c_reg = m ? cn : c_reg;
    h_reg = m ? hn : h_reg;

    // producer: split + pair with neighbor lane -> one u32 word each
    uint32_t p = split_ph2(h_reg);
    uint32_t pp = __shfl_xor(p, 1);
    uint32_t wword = (uu & 1) ? ((pp >> 16) | (p & 0xffff0000u))
                              : ((p & 0xffffu) | (pp << 16));
    __hip_atomic_store(hbuf + (size_t)((s + 1) & 1)*65536 + bgoff + widx,
                       wword, __ATOMIC_RELAXED, __HIP_MEMORY_SCOPE_SYSTEM);
    asm volatile("s_waitcnt vmcnt(0)" ::: "memory");
    __syncthreads();                     // D: all h writes in LLC
    if (tid == 0)
      __hip_atomic_store(flags + bg*32 + hs, (uint32_t)(s + 1),
                         __ATOMIC_RELAXED, __HIP_MEMORY_SCOPE_SYSTEM);
    // y store off the release path (linear ph2 layout, reuses split word)
    ybuf[(size_t)s*65536 + (size_t)bglob*512 + hs*16 + uu] = m ? p : 0u;
  }
  cbuf[(size_t)bglob*512 + hs*16 + uu] = c_reg;
}

// ---------------------------------------------------------------------------
// small epilogue kernels
// ---------------------------------------------------------------------------
__global__ __launch_bounds__(256) void k_pack2(const float* __restrict__ a,
    const float* __restrict__ b, uint32_t* __restrict__ out)
{
  int i = blockIdx.x*256 + threadIdx.x;
  int bb = i >> 10, k = i & 1023;
  float x = (k < 512) ? a[(size_t)bb*512 + k] : b[(size_t)bb*512 + k - 512];
  out[i] = split_ph2(x);
}

__global__ __launch_bounds__(256) void k_pack1(const float* __restrict__ a,
    uint32_t* __restrict__ out)
{ int i = blockIdx.x*256 + threadIdx.x; out[i] = split_ph2(a[i]); }

__global__ __launch_bounds__(256) void k_tanh_split(const float* __restrict__ c,
    uint32_t* __restrict__ hp)
{ int i = blockIdx.x*256 + threadIdx.x; hp[i] = split_ph2(tanhf(c[i])); }

__global__ __launch_bounds__(256) void k_dec_cell(const float* __restrict__ g,
    const float* __restrict__ cdec, float* __restrict__ hout, float* __restrict__ dh)
{
  int i = blockIdx.x*256 + threadIdx.x;     // 65536
  int b = i >> 9, u = i & 511;
  const float* gb = g + (size_t)b*2048;
  float c = sigm(gb[512 + u])*cdec[i] + sigm(gb[u])*tanhf(gb[1024 + u]);
  float h = sigm(gb[1536 + u])*tanhf(c);
  hout[i] = h; dh[i] = h;
}

// scores -> masked softmax -> context (one block per batch row)
__global__ __launch_bounds__(256) void k_attn(const uint32_t* __restrict__ y1,
    const float* __restrict__ h, const int* __restrict__ lens,
    float* __restrict__ ctx, float* __restrict__ dctx)
{
  __shared__ float hsh[512];
  __shared__ float sc[256];
  __shared__ float red[8];
  const int b = blockIdx.x, tid = threadIdx.x, lane = tid & 63, wv = tid >> 6;
  hsh[tid]       = h[(size_t)b*512 + tid];
  hsh[tid + 256] = h[(size_t)b*512 + tid + 256];
  const int len = lens[b];
  __syncthreads();

  for (int it = 0; it < 64; ++it) {
    int s = wv*64 + it;
    const uint32_t* yp = y1 + ((size_t)s*128 + b)*512 + lane*8;
    uint4 p0 = *(const uint4*)yp, p1 = *(const uint4*)(yp + 4);
    uint32_t pv[8] = {p0.x,p0.y,p0.z,p0.w,p1.x,p1.y,p1.z,p1.w};
    float d = 0.f;
#pragma unroll
    for (int e = 0; e < 8; ++e) d += ph2val(pv[e]) * hsh[lane*8 + e];
    for (int off = 32; off; off >>= 1) d += __shfl_xor(d, off);
    if (lane == 0) sc[s] = d;
  }
  __syncthreads();

  float v = (tid < len) ? sc[tid] : -INFINITY;
  float mx = v;
  for (int off = 32; off; off >>= 1) mx = fmaxf(mx, __shfl_xor(mx, off));
  if (lane == 0) red[wv] = mx;
  __syncthreads();
  mx = fmaxf(fmaxf(red[0], red[1]), fmaxf(red[2], red[3]));
  float e = (tid < len) ? expf(v - mx) : 0.f;
  float ssum = e;
  for (int off = 32; off; off >>= 1) ssum += __shfl_xor(ssum, off);
  if (lane == 0) red[4 + wv] = ssum;
  __syncthreads();
  float tot = red[4] + red[5] + red[6] + red[7];
  __syncthreads();
  sc[tid] = e / tot;
  __syncthreads();

  float acc0 = 0.f, acc1 = 0.f;
  for (int s = 0; s < 256; ++s) {
    float w = sc[s];
    const uint32_t* yp = y1 + ((size_t)s*128 + b)*512;
    acc0 += w * ph2val(yp[tid]);
    acc1 += w * ph2val(yp[tid + 256]);
  }
  ctx [(size_t)b*512 + tid]       = acc0;  ctx [(size_t)b*512 + tid + 256] = acc1;
  dctx[(size_t)b*512 + tid]       = acc0;  dctx[(size_t)b*512 + tid + 256] = acc1;
}

__global__ __launch_bounds__(256) void k_argmax(const float* __restrict__ logits,
    float* __restrict__ out)
{
  __shared__ float bv[256];
  __shared__ int   bi[256];
  const int b = blockIdx.x, tid = threadIdx.x;
  const float* L = logits + (size_t)b*32000;
  float best = -INFINITY; int idx = 0;
  for (int i = tid; i < 32000; i += 256) {
    float v = L[i];
    if (v > best) { best = v; idx = i; }
  }
  bv[tid] = best; bi[tid] = idx;
  __syncthreads();
  for (int sft = 128; sft; sft >>= 1) {
    if (tid < sft) {
      if (bv[tid+sft] > bv[tid] || (bv[tid+sft] == bv[tid] && bi[tid+sft] < bi[tid])) {
        bv[tid] = bv[tid+sft]; bi[tid] = bi[tid+sft];
      }
    }
    __syncthreads();
  }
  if (tid == 0) out[b] = (float)bi[0];
}

// ---------------------------------------------------------------------------
// launcher
// ---------------------------------------------------------------------------
extern "C" void kernel_launch(void* const* d_in, const int* in_sizes, int n_in,
                              void* d_out, int out_size, void* d_ws, size_t ws_size,
                              hipStream_t stream)
{
  (void)in_sizes; (void)n_in; (void)out_size;
  const int*   src_tokens = (const int*)  d_in[0];
  const int*   src_lens   = (const int*)  d_in[1];
  const int*   trg_tokens = (const int*)  d_in[2];
  const float* src_emb    = (const float*)d_in[3];
  const float* trg_emb    = (const float*)d_in[4];
  const float* Wih0 = (const float*)d_in[5];
  const float* Whh0 = (const float*)d_in[6];
  const float* bih0 = (const float*)d_in[7];
  const float* bhh0 = (const float*)d_in[8];
  const float* Wih1 = (const float*)d_in[9];
  const float* Whh1 = (const float*)d_in[10];
  const float* bih1 = (const float*)d_in[11];
  const float* bhh1 = (const float*)d_in[12];
  const float* dWih = (const float*)d_in[13];
  const float* dWhh = (const float*)d_in[14];
  const float* dbih = (const float*)d_in[15];
  const float* dbhh = (const float*)d_in[16];
  const float* Winit= (const float*)d_in[17];
  const float* binit= (const float*)d_in[18];
  const float* Whid = (const float*)d_in[19];
  const float* bhid = (const float*)d_in[20];
  const float* Wout = (const float*)d_in[21];
  const float* bout = (const float*)d_in[22];

  uint8_t* ws = (uint8_t*)d_ws;
  constexpr size_t MBs = 1ull << 20;
  constexpr size_t OFF_AP    = 0;                         // 64MB ph2 (src embeds; later Y1)
  constexpr size_t OFF_Y0    = 64*MBs;                    // 64MB ph2
  constexpr size_t OFF_XG    = 128*MBs;                   // 64MB f32 (Xg chunk)
  constexpr size_t OFF_HBUF  = 192*MBs;                   // 512KB
  constexpr size_t OFF_CB0   = OFF_HBUF  + 512*1024;      // 256KB
  constexpr size_t OFF_CB1   = OFF_CB0   + 256*1024;      // 256KB
  constexpr size_t OFF_FLG   = OFF_CB1   + 256*1024;      // 4KB
  constexpr size_t OFF_PK    = OFF_FLG   + 4096;          // 512KB
  constexpr size_t OFF_CDEC  = OFF_PK    + 512*1024;      // 256KB
  constexpr size_t OFF_HDECP = OFF_CDEC  + 256*1024;      // 256KB ph2
  constexpr size_t OFF_EMBP  = OFF_HDECP + 256*1024;      // 256KB ph2
  constexpr size_t OFF_G     = OFF_EMBP  + 256*1024;      // 1MB f32
  constexpr size_t OFF_HDEC2 = OFF_G     + 1*MBs;         // 256KB f32
  constexpr size_t OFF_CTX   = OFF_HDEC2 + 256*1024;      // 256KB f32
  constexpr size_t OFF_AVEC  = OFF_CTX   + 256*1024;      // 256KB f32
  constexpr size_t OFF_AVECP = OFF_AVEC  + 256*1024;      // 256KB ph2
  constexpr size_t OFF_LOG   = OFF_AVECP + 256*1024;      // 16MB f32
  constexpr size_t OFF_WP0   = OFF_LOG   + 16*MBs;        // 4MB ph2 (Wih0)
  constexpr size_t OFF_WP1   = OFF_WP0   + 4*MBs;         // 4MB ph2 (Wih1)
  constexpr size_t WS_NEED_WP = OFF_WP1 + 4*MBs;

  uint32_t* Ap    = (uint32_t*)(ws + OFF_AP);
  uint32_t* Y0    = (uint32_t*)(ws + OFF_Y0);
  uint32_t* Y1    = (uint32_t*)(ws + OFF_AP);     // reuse after layer 0
  float*    Xg    = (float*)   (ws + OFF_XG);
  uint32_t* hbuf  = (uint32_t*)(ws + OFF_HBUF);
  float*    cb0   = (float*)   (ws + OFF_CB0);
  float*    cb1   = (float*)   (ws + OFF_CB1);
  uint32_t* flg   = (uint32_t*)(ws + OFF_FLG);
  uint32_t* pk    = (uint32_t*)(ws + OFF_PK);
  float*    cdec  = (float*)   (ws + OFF_CDEC);
  uint32_t* hdecp = (uint32_t*)(ws + OFF_HDECP);
  uint32_t* embp  = (uint32_t*)(ws + OFF_EMBP);
  float*    g     = (float*)   (ws + OFF_G);
  float*    hdec2 = (float*)   (ws + OFF_HDEC2);
  float*    ctx   = (float*)   (ws + OFF_CTX);
  float*    avec  = (float*)   (ws + OFF_AVEC);
  uint32_t* avecp = (uint32_t*)(ws + OFF_AVECP);
  float*    logit = (float*)   (ws + OFF_LOG);
  uint32_t* Wp0   = (uint32_t*)(ws + OFF_WP0);
  uint32_t* Wp1   = (uint32_t*)(ws + OFF_WP1);
  float*    dout  = (float*)   d_out;

  const bool useWp = (ws_size >= WS_NEED_WP);

  // ---- one-time: pre-split encoder input weights to ph2 ----
  if (useWp) {
    k_pack1<<<4096, 256, 0, stream>>>(Wih0, Wp0);   // 2048x512
    k_pack1<<<4096, 256, 0, stream>>>(Wih1, Wp1);
  }

  // ---- encoder layer 0 ----
  hipMemsetAsync(flg,  0, 1024, stream);
  hipMemsetAsync(hbuf, 0, 2*65536*4, stream);
  hipMemsetAsync(cb0,  0, 65536*4, stream);
  k_embed_src<<<2048, 256, 0, stream>>>(src_tokens, src_emb, Ap);
  for (int c = 0; c < 4; ++c) {
    int s0 = c * 64;
    if (useWp)
      k_gemm<<<dim3(16, 64), 256, 0, stream>>>(Ap + (size_t)s0*128*512, 512,
          Wp0, 512, 1, bih0, bhh0, Xg, 2048, 512, 0);
    else
      k_gemm<<<dim3(16, 64), 256, 0, stream>>>(Ap + (size_t)s0*128*512, 512,
          Wih0, 512, 0, bih0, bhh0, Xg, 2048, 512, 0);
    k_lstm<<<256, 256, 0, stream>>>(Whh0, Xg, src_lens, hbuf, cb0, Y0, flg, s0, 64);
  }
  // ---- encoder layer 1 ----
  hipMemsetAsync(flg,  0, 1024, stream);
  hipMemsetAsync(hbuf, 0, 2*65536*4, stream);
  hipMemsetAsync(cb1,  0, 65536*4, stream);
  for (int c = 0; c < 4; ++c) {
    int s0 = c * 64;
    if (useWp)
      k_gemm<<<dim3(16, 64), 256, 0, stream>>>(Y0 + (size_t)s0*128*512, 512,
          Wp1, 512, 1, bih1, bhh1, Xg, 2048, 512, 0);
    else
      k_gemm<<<dim3(16, 64), 256, 0, stream>>>(Y0 + (size_t)s0*128*512, 512,
          Wih1, 512, 0, bih1, bhh1, Xg, 2048, 512, 0);
    k_lstm<<<256, 256, 0, stream>>>(Whh1, Xg, src_lens, hbuf, cb1, Y1, flg, s0, 64);
  }

  // ---- decoder init ----
  k_pack2<<<512, 256, 0, stream>>>(cb0, cb1, pk);
  k_gemm<<<dim3(4, 1), 256, 0, stream>>>(pk, 1024, Winit, 1024, 0, binit, nullptr,
      cdec, 512, 1024, 0);
  k_tanh_split<<<256, 256, 0, stream>>>(cdec, hdecp);

  // ---- decoder LSTM step ----
  k_embed_trg<<<256, 256, 0, stream>>>(trg_tokens, trg_emb, embp);
  k_gemm<<<dim3(16, 1), 256, 0, stream>>>(embp, 512, dWih, 1024, 0, dbih, dbhh,
      g, 2048, 512, 0);
  k_gemm<<<dim3(16, 1), 256, 0, stream>>>(hdecp, 512, dWhh, 512, 0, nullptr, nullptr,
      g, 2048, 512, 1);
  k_dec_cell<<<256, 256, 0, stream>>>(g, cdec, hdec2, dout + 65536);

  // ---- attention ----
  k_attn<<<128, 256, 0, stream>>>(Y1, hdec2, src_lens, ctx, dout);

  // ---- output projection + argmax ----
  k_pack2<<<512, 256, 0, stream>>>(hdec2, ctx, pk);
  k_gemm<<<dim3(4, 1), 256, 0, stream>>>(pk, 1024, Whid, 1024, 0, bhid, nullptr,
      avec, 512, 1024, 0);
  k_pack1<<<256, 256, 0, stream>>>(avec, avecp);
  k_gemm<<<dim3(250, 1), 256, 0, stream>>>(avecp, 512, Wout, 512, 0, bout, nullptr,
      logit, 32000, 512, 0);
  k_argmax<<<128, 256, 0, stream>>>(logit, dout + 131072);
}